// Round 14
// baseline (41.945 us; speedup 1.0000x reference)
//
#include <hip/hip_runtime.h>
#include <hip/hip_bf16.h>

#define D_IN   256
#define UNITS  128
#define LORA_R 4
#define ROWS_PER_TILE   16
#define TILES_PER_BLOCK 16     // 256 rows per block
#define GRID_GEMM       512    // 512 * 256 = 131072 rows; 2/CU -> ALL co-resident

typedef __attribute__((ext_vector_type(8))) short short8;
typedef __attribute__((ext_vector_type(4))) float f32x4;
typedef __attribute__((ext_vector_type(2))) float f32x2;

// raw barrier WITH compile-time memory ordering (no vmcnt(0) drain, unlike
// __syncthreads) and counted vmcnt waits (T3/T4: loads/stores stay in flight)
#define BARRIER()  asm volatile("s_barrier" ::: "memory")
#define VMCNT(n)   asm volatile("s_waitcnt vmcnt(" #n ")" ::: "memory")
// pin issue order == source order around each stage (R10 failure mode: the
// scheduler may sink gll16 below the phase's non-aliasing global stores,
// silently invalidating the hand-counted VMCNT literals).
#define SCHED_FENCE() __builtin_amdgcn_sched_barrier(0)

// async global->LDS, 16B per lane. ldsptr is the WAVE-UNIFORM base;
// HW stores lane l's 16B at base + l*16 (m104/m108).
static __device__ __forceinline__ void gll16(const void* g, void* l) {
    __builtin_amdgcn_global_load_lds(
        (const __attribute__((address_space(1))) unsigned int*)g,
        (__attribute__((address_space(3))) unsigned int*)l,
        16, 0, 0);
}

// Fully fused: out = relu(x @ (kernel + A[idx]@B[idx]) + bias + db[idx])
// R12 structure (single generation: 512 blocks x 2/CU, 4 LDS bufs, 8 phases
// x 2 tiles, ONE barrier/phase) + WIDE STORES:
//   The MFMA internal-col -> output-col mapping is ours (we pack W), so map
//   acc0/acc1 to ADJACENT columns: lane rlo owns cols wave*32 + 2*rlo (+1).
//   {acc0[j],acc1[j]} then merge into ONE dwordx2 store -> 4 stores/tile
//   (was 8 dwords), each 16-lane segment 128B contiguous.
//
// vmcnt accounting (in-order retirement; stage-pair = 8 VMEM, phase stores
// = 2 tiles x 4 = 8 VMEM). At phase p's wait, the target stage-pair was
// issued in phase p-1 BEFORE that phase's stores -> newer-outstanding = 8
// stores -> VMCNT(8). Phase 0's target pair is the prologue pair with
// nothing newer outstanding (W-prologue loads all consumed) -> VMCNT(0).
// Buffer safety: stage-pair at phase p writes the buf pair last read during
// phase p-1, which completed before barrier_p on every wave.
__global__ __launch_bounds__(256, 2) void mlora_fused(
    const float* __restrict__ x,
    const int*   __restrict__ dom,
    const float* __restrict__ a_kernel,
    const float* __restrict__ b_kernel,
    const float* __restrict__ domain_bias,
    const float* __restrict__ kernel,
    const float* __restrict__ bias,
    float* __restrict__ out) {
    __shared__ float lds[4][ROWS_PER_TILE * 256];   // 4 x 16 KiB
    const int lane = threadIdx.x & 63;
    const int wave = threadIdx.x >> 6;   // 0..3
    const int rlo = lane & 15;
    const int g = lane >> 4;

    const size_t block_row0 = (size_t)blockIdx.x * (ROWS_PER_TILE * TILES_PER_BLOCK);
    const int swz = (rlo & 7) << 4;

    // stage tile -> lds[buf]: wave w loads tile-rows w*4 .. w*4+3, one
    // global_load_lds (1 KiB, source chunk (lane) ^ (row&7)) per row.
    auto stage = [&](int bufi, int tile) {
        const char* gbase = (const char*)x +
            (block_row0 + (size_t)tile * ROWS_PER_TILE + wave * 4) * 1024;
        char* lbase = (char*)&lds[bufi][0] + (size_t)wave * 4 * 1024;
#pragma unroll
        for (int i = 0; i < 4; ++i) {
            const int rsw = (wave * 4 + i) & 7;
            gll16(gbase + (size_t)i * 1024 + ((lane * 16) ^ (rsw << 4)),
                  lbase + (size_t)i * 1024);
        }
    };

    // ---- issue prologue pair NOW; W-prologue hides under their latency
    stage(0, 0);
    SCHED_FENCE();
    stage(1, 1);
    SCHED_FENCE();

    // ---- W-prologue (registers only; sched_barriers cap transient pressure)
    // Column mapping (NEW): lane owns output cols c0 = wave*32 + 2*rlo and
    // c1 = c0 + 1 (adjacent) -> enables dwordx2 C-stores. Any injective
    // internal-col->output-col map is valid as long as W-pack and store agree.
    const int idx = dom[0];
    const float* __restrict__ A  = a_kernel + (size_t)idx * D_IN * LORA_R;
    const float* __restrict__ Bm = b_kernel + (size_t)idx * LORA_R * UNITS;

    const int c0 = wave * 32 + 2 * rlo, c1 = c0 + 1;
    const float b0 = bias[c0] + domain_bias[(size_t)idx * UNITS + c0];
    const float b1 = bias[c1] + domain_bias[(size_t)idx * UNITS + c1];

    f32x4 bv0 = { Bm[0 * UNITS + c0], Bm[1 * UNITS + c0],
                  Bm[2 * UNITS + c0], Bm[3 * UNITS + c0] };
    f32x4 bv1 = { Bm[0 * UNITS + c1], Bm[1 * UNITS + c1],
                  Bm[2 * UNITS + c1], Bm[3 * UNITS + c1] };

    short8 bfrag[8][2];
#pragma unroll
    for (int s = 0; s < 8; ++s) {
        const int k0 = s * 32 + g * 8;
#pragma unroll
        for (int tt = 0; tt < 2; ++tt) {
            const int n = tt ? c1 : c0;
            const f32x4 bv = tt ? bv1 : bv0;
            union { short8 s8; __hip_bfloat162 h2[4]; } w;
#pragma unroll
            for (int jj = 0; jj < 4; ++jj) {
                const int k = k0 + 2 * jj;
                f32x4 a0 = *reinterpret_cast<const f32x4*>(A + (size_t)k * 4);
                f32x4 a1 = *reinterpret_cast<const f32x4*>(A + (size_t)k * 4 + 4);
                float w0 = kernel[(size_t)k * UNITS + n]
                         + a0[0] * bv[0] + a0[1] * bv[1]
                         + a0[2] * bv[2] + a0[3] * bv[3];
                float w1 = kernel[(size_t)(k + 1) * UNITS + n]
                         + a1[0] * bv[0] + a1[1] * bv[1]
                         + a1[2] * bv[2] + a1[3] * bv[3];
                w.h2[jj] = __float22bfloat162_rn(make_float2(w0, w1));
            }
            bfrag[s][tt] = w.s8;
        }
        __builtin_amdgcn_sched_barrier(0);   // cap load clustering per s-step
    }

    // verified compute body (swizzled LDS reads, cvt_pk, 16 MFMA) + x2 stores
    auto compute_tile = [&](int bufi, int tile) {
        const size_t r0g = block_row0 + (size_t)tile * ROWS_PER_TILE;
        const char* lrow = (const char*)&lds[bufi][0] + (size_t)rlo * 1024;
        f32x4 acc0 = {0.f, 0.f, 0.f, 0.f};
        f32x4 acc1 = {0.f, 0.f, 0.f, 0.f};
#pragma unroll
        for (int s = 0; s < 8; ++s) {
            const int base = s * 128 + g * 32;
            f32x4 u0 = *reinterpret_cast<const f32x4*>(lrow + (base ^ swz));
            f32x4 u1 = *reinterpret_cast<const f32x4*>(lrow + ((base + 16) ^ swz));
            union { short8 s8; __hip_bfloat162 h2[4]; } af;
            af.h2[0] = __float22bfloat162_rn(make_float2(u0[0], u0[1]));
            af.h2[1] = __float22bfloat162_rn(make_float2(u0[2], u0[3]));
            af.h2[2] = __float22bfloat162_rn(make_float2(u1[0], u1[1]));
            af.h2[3] = __float22bfloat162_rn(make_float2(u1[2], u1[3]));
            acc0 = __builtin_amdgcn_mfma_f32_16x16x32_bf16(af.s8, bfrag[s][0], acc0, 0, 0, 0);
            acc1 = __builtin_amdgcn_mfma_f32_16x16x32_bf16(af.s8, bfrag[s][1], acc1, 0, 0, 0);
        }
        // D layout: row = r0g + g*4 + j; cols c0, c1 ADJACENT -> dwordx2
        float* op = out + (r0g + g * 4) * UNITS + c0;
#pragma unroll
        for (int j = 0; j < 4; ++j) {
            f32x2 v = { fmaxf(acc0[j] + b0, 0.f), fmaxf(acc1[j] + b1, 0.f) };
            *reinterpret_cast<f32x2*>(op + (size_t)j * UNITS) = v;
        }
    };

    // ---- 8 phases x 2 tiles; ONE barrier per phase; stages pinned.
    VMCNT(0);  BARRIER(); stage(2, 2);  SCHED_FENCE(); stage(3, 3);  SCHED_FENCE();
               compute_tile(0, 0);  compute_tile(1, 1);
    VMCNT(8);  BARRIER(); stage(0, 4);  SCHED_FENCE(); stage(1, 5);  SCHED_FENCE();
               compute_tile(2, 2);  compute_tile(3, 3);
    VMCNT(8);  BARRIER(); stage(2, 6);  SCHED_FENCE(); stage(3, 7);  SCHED_FENCE();
               compute_tile(0, 4);  compute_tile(1, 5);
    VMCNT(8);  BARRIER(); stage(0, 8);  SCHED_FENCE(); stage(1, 9);  SCHED_FENCE();
               compute_tile(2, 6);  compute_tile(3, 7);
    VMCNT(8);  BARRIER(); stage(2, 10); SCHED_FENCE(); stage(3, 11); SCHED_FENCE();
               compute_tile(0, 8);  compute_tile(1, 9);
    VMCNT(8);  BARRIER(); stage(0, 12); SCHED_FENCE(); stage(1, 13); SCHED_FENCE();
               compute_tile(2, 10); compute_tile(3, 11);
    VMCNT(8);  BARRIER(); stage(2, 14); SCHED_FENCE(); stage(3, 15); SCHED_FENCE();
               compute_tile(0, 12); compute_tile(1, 13);
    VMCNT(8);  BARRIER();
               compute_tile(2, 14); compute_tile(3, 15);
}

extern "C" void kernel_launch(void* const* d_in, const int* in_sizes, int n_in,
                              void* d_out, int out_size, void* d_ws, size_t ws_size,
                              hipStream_t stream) {
    const float* x           = (const float*)d_in[0];
    const int*   dom         = (const int*)d_in[1];
    const float* a_kernel    = (const float*)d_in[2];
    const float* b_kernel    = (const float*)d_in[3];
    const float* domain_bias = (const float*)d_in[4];
    const float* kernel      = (const float*)d_in[5];
    const float* bias        = (const float*)d_in[6];
    float* out = (float*)d_out;
    (void)d_ws; (void)ws_size;

    mlora_fused<<<GRID_GEMM, 256, 0, stream>>>(x, dom, a_kernel, b_kernel,
                                               domain_bias, kernel, bias, out);
}

// Round 15
// 39.685 us; speedup vs baseline: 1.0570x; 1.0570x over previous
//
#include <hip/hip_runtime.h>
#include <hip/hip_bf16.h>

#define D_IN   256
#define UNITS  128
#define LORA_R 4
#define ROWS_PER_TILE   16
#define TILES_PER_BLOCK 16     // 256 rows per block
#define GRID_GEMM       512    // 512 * 256 = 131072 rows; 2/CU -> ALL co-resident

typedef __attribute__((ext_vector_type(8))) short short8;
typedef __attribute__((ext_vector_type(4))) float f32x4;

// raw barrier WITH compile-time memory ordering (no vmcnt(0) drain, unlike
// __syncthreads) and counted vmcnt waits (T3/T4: loads/stores stay in flight)
#define BARRIER()  asm volatile("s_barrier" ::: "memory")
#define VMCNT(n)   asm volatile("s_waitcnt vmcnt(" #n ")" ::: "memory")
// pin issue order == source order around each stage (R10 failure mode: the
// scheduler may sink gll16 below the phase's non-aliasing global stores,
// silently invalidating the hand-counted VMCNT literals).
#define SCHED_FENCE() __builtin_amdgcn_sched_barrier(0)

// async global->LDS, 16B per lane. ldsptr is the WAVE-UNIFORM base;
// HW stores lane l's 16B at base + l*16 (m104/m108).
static __device__ __forceinline__ void gll16(const void* g, void* l) {
    __builtin_amdgcn_global_load_lds(
        (const __attribute__((address_space(1))) unsigned int*)g,
        (__attribute__((address_space(3))) unsigned int*)l,
        16, 0, 0);
}

// Fully fused: out = relu(x @ (kernel + A[idx]@B[idx]) + bias + db[idx])
// BEST-MEASURED CONFIG (R12, 39.97us): single generation (512 blocks x 2/CU,
// all co-resident), 4 LDS buffers, prefetch distance 3, ONE barrier/tile.
//
// Per-wave pinned issue order:
//   st0 st1 st2 [W-loads, compiler-drained] |
//   t=0..12:  V B st_{t+3} c_t      t=13..15: V B c_t
// newer-than-st_t at its wait (stage=4 VMEM, compute stores=8 VMEM):
//   steady (t=3..13): stores_{t-3,t-2,t-1}(24) + st_{t+1},st_{t+2}(8) = 32
//   t=14: stores11(8)+st15(4)+stores12(8)+stores13(8) = 28
//   t=15: stores12+stores13+stores14 = 24
//   t=0..2: st0..st2 already retired (compiler drains them consuming the
//   W-loads issued after them) -> V(32) is trivially safe.
// Buffer safety: stage at tile t writes buf (t+3)%4 = buf (t-1)%4; its last
// reader is compute(t-1), which precedes barrier_t on every wave.
__global__ __launch_bounds__(256, 2) void mlora_fused(
    const float* __restrict__ x,
    const int*   __restrict__ dom,
    const float* __restrict__ a_kernel,
    const float* __restrict__ b_kernel,
    const float* __restrict__ domain_bias,
    const float* __restrict__ kernel,
    const float* __restrict__ bias,
    float* __restrict__ out) {
    __shared__ float lds[4][ROWS_PER_TILE * 256];   // 4 x 16 KiB
    const int lane = threadIdx.x & 63;
    const int wave = threadIdx.x >> 6;   // 0..3
    const int t0 = wave * 2;             // first N-tile (cols 32w..32w+31)
    const int rlo = lane & 15;
    const int g = lane >> 4;

    const size_t block_row0 = (size_t)blockIdx.x * (ROWS_PER_TILE * TILES_PER_BLOCK);
    const int swz = (rlo & 7) << 4;

    // stage tile -> lds[buf]: wave w loads tile-rows w*4 .. w*4+3, one
    // global_load_lds (1 KiB, source chunk (lane) ^ (row&7)) per row.
    auto stage = [&](int bufi, int tile) {
        const char* gbase = (const char*)x +
            (block_row0 + (size_t)tile * ROWS_PER_TILE + wave * 4) * 1024;
        char* lbase = (char*)&lds[bufi][0] + (size_t)wave * 4 * 1024;
#pragma unroll
        for (int i = 0; i < 4; ++i) {
            const int rsw = (wave * 4 + i) & 7;
            gll16(gbase + (size_t)i * 1024 + ((lane * 16) ^ (rsw << 4)),
                  lbase + (size_t)i * 1024);
        }
    };

    // ---- issue first three tile stages NOW; prologue hides under their latency
    stage(0, 0);
    SCHED_FENCE();
    stage(1, 1);
    SCHED_FENCE();
    stage(2, 2);
    SCHED_FENCE();

    // ---- W-prologue (registers only; sched_barriers cap transient pressure)
    const int idx = dom[0];
    const float* __restrict__ A  = a_kernel + (size_t)idx * D_IN * LORA_R;
    const float* __restrict__ Bm = b_kernel + (size_t)idx * LORA_R * UNITS;

    const int c0 = t0 * 16 + rlo, c1 = c0 + 16;
    const float b0 = bias[c0] + domain_bias[(size_t)idx * UNITS + c0];
    const float b1 = bias[c1] + domain_bias[(size_t)idx * UNITS + c1];

    f32x4 bv0 = { Bm[0 * UNITS + c0], Bm[1 * UNITS + c0],
                  Bm[2 * UNITS + c0], Bm[3 * UNITS + c0] };
    f32x4 bv1 = { Bm[0 * UNITS + c1], Bm[1 * UNITS + c1],
                  Bm[2 * UNITS + c1], Bm[3 * UNITS + c1] };

    short8 bfrag[8][2];
#pragma unroll
    for (int s = 0; s < 8; ++s) {
        const int k0 = s * 32 + g * 8;
#pragma unroll
        for (int tt = 0; tt < 2; ++tt) {
            const int n = tt ? c1 : c0;
            const f32x4 bv = tt ? bv1 : bv0;
            union { short8 s8; __hip_bfloat162 h2[4]; } w;
#pragma unroll
            for (int jj = 0; jj < 4; ++jj) {
                const int k = k0 + 2 * jj;
                f32x4 a0 = *reinterpret_cast<const f32x4*>(A + (size_t)k * 4);
                f32x4 a1 = *reinterpret_cast<const f32x4*>(A + (size_t)k * 4 + 4);
                float w0 = kernel[(size_t)k * UNITS + n]
                         + a0[0] * bv[0] + a0[1] * bv[1]
                         + a0[2] * bv[2] + a0[3] * bv[3];
                float w1 = kernel[(size_t)(k + 1) * UNITS + n]
                         + a1[0] * bv[0] + a1[1] * bv[1]
                         + a1[2] * bv[2] + a1[3] * bv[3];
                w.h2[jj] = __float22bfloat162_rn(make_float2(w0, w1));
            }
            bfrag[s][tt] = w.s8;
        }
        __builtin_amdgcn_sched_barrier(0);   // cap load clustering per s-step
    }

    // verified compute body (swizzled LDS reads, cvt_pk, 16 MFMA, 8 stores)
    auto compute_tile = [&](int bufi, int tile) {
        const size_t r0g = block_row0 + (size_t)tile * ROWS_PER_TILE;
        const char* lrow = (const char*)&lds[bufi][0] + (size_t)rlo * 1024;
        f32x4 acc0 = {0.f, 0.f, 0.f, 0.f};
        f32x4 acc1 = {0.f, 0.f, 0.f, 0.f};
#pragma unroll
        for (int s = 0; s < 8; ++s) {
            const int base = s * 128 + g * 32;
            f32x4 u0 = *reinterpret_cast<const f32x4*>(lrow + (base ^ swz));
            f32x4 u1 = *reinterpret_cast<const f32x4*>(lrow + ((base + 16) ^ swz));
            union { short8 s8; __hip_bfloat162 h2[4]; } af;
            af.h2[0] = __float22bfloat162_rn(make_float2(u0[0], u0[1]));
            af.h2[1] = __float22bfloat162_rn(make_float2(u0[2], u0[3]));
            af.h2[2] = __float22bfloat162_rn(make_float2(u1[0], u1[1]));
            af.h2[3] = __float22bfloat162_rn(make_float2(u1[2], u1[3]));
            acc0 = __builtin_amdgcn_mfma_f32_16x16x32_bf16(af.s8, bfrag[s][0], acc0, 0, 0, 0);
            acc1 = __builtin_amdgcn_mfma_f32_16x16x32_bf16(af.s8, bfrag[s][1], acc1, 0, 0, 0);
        }
        // D layout: row = r0g + g*4 + j, col = tile*16 + rlo
        float* op = out + (r0g + g * 4) * UNITS;
#pragma unroll
        for (int j = 0; j < 4; ++j) {
            op[(size_t)j * UNITS + t0 * 16 + rlo]      = fmaxf(acc0[j] + b0, 0.f);
            op[(size_t)j * UNITS + t0 * 16 + 16 + rlo] = fmaxf(acc1[j] + b1, 0.f);
        }
    };

    // ---- pipeline: ONE barrier per tile; stage pinned after the barrier.
    VMCNT(32); BARRIER(); stage(3, 3);  SCHED_FENCE(); compute_tile(0, 0);
    VMCNT(32); BARRIER(); stage(0, 4);  SCHED_FENCE(); compute_tile(1, 1);
    VMCNT(32); BARRIER(); stage(1, 5);  SCHED_FENCE(); compute_tile(2, 2);
    VMCNT(32); BARRIER(); stage(2, 6);  SCHED_FENCE(); compute_tile(3, 3);
    VMCNT(32); BARRIER(); stage(3, 7);  SCHED_FENCE(); compute_tile(0, 4);
    VMCNT(32); BARRIER(); stage(0, 8);  SCHED_FENCE(); compute_tile(1, 5);
    VMCNT(32); BARRIER(); stage(1, 9);  SCHED_FENCE(); compute_tile(2, 6);
    VMCNT(32); BARRIER(); stage(2, 10); SCHED_FENCE(); compute_tile(3, 7);
    VMCNT(32); BARRIER(); stage(3, 11); SCHED_FENCE(); compute_tile(0, 8);
    VMCNT(32); BARRIER(); stage(0, 12); SCHED_FENCE(); compute_tile(1, 9);
    VMCNT(32); BARRIER(); stage(1, 13); SCHED_FENCE(); compute_tile(2, 10);
    VMCNT(32); BARRIER(); stage(2, 14); SCHED_FENCE(); compute_tile(3, 11);
    VMCNT(32); BARRIER(); stage(3, 15); SCHED_FENCE(); compute_tile(0, 12);
    VMCNT(32); BARRIER();                              compute_tile(1, 13);
    VMCNT(28); BARRIER();                              compute_tile(2, 14);
    VMCNT(24); BARRIER();                              compute_tile(3, 15);
}

extern "C" void kernel_launch(void* const* d_in, const int* in_sizes, int n_in,
                              void* d_out, int out_size, void* d_ws, size_t ws_size,
                              hipStream_t stream) {
    const float* x           = (const float*)d_in[0];
    const int*   dom         = (const int*)d_in[1];
    const float* a_kernel    = (const float*)d_in[2];
    const float* b_kernel    = (const float*)d_in[3];
    const float* domain_bias = (const float*)d_in[4];
    const float* kernel      = (const float*)d_in[5];
    const float* bias        = (const float*)d_in[6];
    float* out = (float*)d_out;
    (void)d_ws; (void)ws_size;

    mlora_fused<<<GRID_GEMM, 256, 0, stream>>>(x, dom, a_kernel, b_kernel,
                                               domain_bias, kernel, bias, out);
}